// Round 22
// baseline (164.762 us; speedup 1.0000x reference)
//
#include <hip/hip_runtime.h>
#include <hip/hip_bf16.h>
#include <stdint.h>

#define CDIM 512
#define WDIM 2048
#define BDIM 8
#define NGRP 32
#define LOG2E 1.4426950408889634f

typedef unsigned short u16;
typedef unsigned char u8;
typedef __attribute__((ext_vector_type(8))) short bf16x8;
typedef __attribute__((ext_vector_type(4))) float f32x4;
typedef __attribute__((ext_vector_type(2))) long long2v;

__device__ __forceinline__ float bf2f(u16 u) {
  return __builtin_bit_cast(float, (uint32_t)(u) << 16);
}
__device__ __forceinline__ u16 f2bf(float f) {
  return __builtin_bit_cast(u16, __float2bfloat16(f));
}
__device__ __forceinline__ u8 f2f8(float f) {
  // OCP e4m3 via HW cvt (saturating); our values are far from 448.
  return (u8)(__builtin_amdgcn_cvt_pk_fp8_f32(f, 0.f, 0, false));
}

__device__ __forceinline__ void gld_lds16(const void* g, void* l) {
  __builtin_amdgcn_global_load_lds(
      (const __attribute__((address_space(1))) uint32_t*)(uintptr_t)(g),
      (__attribute__((address_space(3))) uint32_t*)(uintptr_t)(l),
      16, 0, 0);
}

// fp8 k-octet interleave within each 64-byte k-window: stored 16B chunk c
// holds global octets (c, c+4) -> one ds_read_b128 yields both K=32 slices.
__device__ __forceinline__ int pi64(int l) {
  return ((l >> 3) & 3) * 16 + ((l >> 5) & 1) * 8 + (l & 7);
}

// ---------------- weight fp32 -> bf16 ----------------
__global__ __launch_bounds__(256) void cvt_weights(
    const float* __restrict__ a, const float* __restrict__ b,
    const float* __restrict__ c, const float* __restrict__ d,
    u16* __restrict__ o) {
  int i = blockIdx.x * 256 + threadIdx.x;  // 262144 elements each
  o[i]          = f2bf(a[i]);
  o[262144 + i] = f2bf(b[i]);
  o[524288 + i] = f2bf(c[i]);
  o[786432 + i] = f2bf(d[i]);
}

// ---------------- fused groupnorm: one block per (b,g), x read ONCE --------
__global__ __launch_bounds__(512) void gn_fused(
    const float* __restrict__ x, const float* __restrict__ gamma,
    const float* __restrict__ beta, u16* __restrict__ hT) {
  extern __shared__ u16 hbuf[];            // [16][2052] padded
  __shared__ float red[2][8];
  __shared__ float mrsh[2];
  const int bg = blockIdx.x;               // b*32+g
  const int b = bg >> 5, g = bg & 31;
  const int tid = threadIdx.x;
  const float4* xp = (const float4*)(x + (size_t)bg * 16 * WDIM);
  float s = 0.f, s2 = 0.f;
  for (int i = tid; i < 16 * WDIM / 4; i += 512) {
    float4 v = xp[i];
    s += v.x + v.y + v.z + v.w;
    s2 = fmaf(v.x, v.x, s2); s2 = fmaf(v.y, v.y, s2);
    s2 = fmaf(v.z, v.z, s2); s2 = fmaf(v.w, v.w, s2);
    int e = i * 4;
    int cc = e >> 11, w = e & 2047;
    u16* p = &hbuf[cc * 2052 + w];
    p[0] = f2bf(v.x); p[1] = f2bf(v.y); p[2] = f2bf(v.z); p[3] = f2bf(v.w);
  }
  for (int off = 32; off; off >>= 1) {
    s  += __shfl_xor(s, off, 64);
    s2 += __shfl_xor(s2, off, 64);
  }
  if ((tid & 63) == 0) { red[0][tid >> 6] = s; red[1][tid >> 6] = s2; }
  __syncthreads();
  if (tid == 0) {
    float S = 0.f, S2 = 0.f;
    #pragma unroll
    for (int i = 0; i < 8; ++i) { S += red[0][i]; S2 += red[1][i]; }
    const float inv_n = 1.0f / (16.0f * WDIM);
    float m = S * inv_n;
    float var = S2 * inv_n - m * m;
    mrsh[0] = m; mrsh[1] = rsqrtf(var + 1e-6f);
  }
  __syncthreads();
  const float m = mrsh[0], r = mrsh[1];
  float ga[16], bb[16];
  #pragma unroll
  for (int cc = 0; cc < 16; ++cc) {
    float gm = gamma[g * 16 + cc] * r;
    ga[cc] = gm;
    bb[cc] = beta[g * 16 + cc] - m * gm;
  }
  #pragma unroll
  for (int rr = 0; rr < 4; ++rr) {
    int w = rr * 512 + tid;
    u16 ov[16];
    #pragma unroll
    for (int cc = 0; cc < 16; ++cc)
      ov[cc] = f2bf(fmaf(bf2f(hbuf[cc * 2052 + w]), ga[cc], bb[cc]));
    u16* dst = hT + ((size_t)b * WDIM + w) * CDIM + g * 16;
    *(uint4*)(dst)     = *(const uint4*)(&ov[0]);
    *(uint4*)(dst + 8) = *(const uint4*)(&ov[8]);
  }
}

// ---------------- combine per-block row-sum partials -> 1/rowsum ----------
template <int NP>
__global__ __launch_bounds__(256) void sm_combine(
    const float* __restrict__ lpart, float* __restrict__ linv) {
  int idx = blockIdx.x * 256 + threadIdx.x;   // 16384 = 8*2048
  int b = idx >> 11, i = idx & 2047;
  float l = 0.f;
  #pragma unroll
  for (int p = 0; p < NP; ++p)
    l += lpart[((size_t)b * NP + p) * 2048 + i];
  linv[idx] = 1.0f / l;
}

// ---------------- 8-wave single-phase TN GEMM, bf16 inputs (R16 base) -----
// C[m][n] = sum_k A[m][k]*B[n][k]. BM=128, BN=256, wave tile 64x64.
// BK=32, ring-3 LDS (72KB), stage 2 ahead, counted vmcnt(3), one closing
// barrier per K-tile.  Bijective XCD swizzle; verified conflict-free
// both-sides LDS swizzle (128B super-rows, chunk p at p^(S&7)).
// OutT: float / u16(bf16) / u8(fp8-e4m3 with k-octet interleave pi64).
// BIAS_MODE: 0 none, 2 +bias[m], 3 split-n, 4 *bias[bz*2048+m].
template <int BIAS_MODE, int RESID, int SCALE, typename OutT, int SMEXP>
__global__ __launch_bounds__(512, 1) void gemm_tn(
    const u16* __restrict__ A, const u16* __restrict__ B,
    OutT* __restrict__ Cp, const float* __restrict__ bias,
    const float* __restrict__ bias2, const float* __restrict__ resid,
    float* __restrict__ LP, float scale, int K, int N, int lda, int ldb,
    long sAb, long sBb, long sCb, int gx, int gy) {
  constexpr int BM_ = 128, BN_ = 256;
  constexpr int MI = 4;
  constexpr int CB = 2, L = 3;
  constexpr int ABYTES = BM_ * 64;         // 8192
  constexpr int SLOT = (BM_ + BN_) * 64;   // 24576
  extern __shared__ char smem[];
  const int tid = threadIdx.x;
  const int wave = tid >> 6, lane = tid & 63;
  const int wr = wave >> 2, wc = wave & 3;   // 2(M) x 4(N)
  const int fr = lane & 15, kg = lane >> 4;

  const int nq = gridDim.x >> 3;
  const int sid = (blockIdx.x & 7) * nq + (blockIdx.x >> 3);
  const int bx = sid % gx;
  const int t1 = sid / gx;
  const int by = t1 % gy;
  const int bz = t1 / gy;

  const size_t zc = (size_t)bz * sCb;
  const u16* Ab = A + (size_t)bz * sAb + (size_t)bx * BM_ * lda;
  const u16* Bb = B + (size_t)bz * sBb + (size_t)by * BN_ * ldb;

  int aoff, boff[CB];
  {
    int pc = tid;
    int S = pc >> 3, p = (pc & 7) ^ (S & 7);
    aoff = (2 * S + (p >> 2)) * lda + (p & 3) * 8;
  }
  #pragma unroll
  for (int j = 0; j < CB; ++j) {
    int pc = j * 512 + tid;
    int S = pc >> 3, p = (pc & 7) ^ (S & 7);
    boff[j] = (2 * S + (p >> 2)) * ldb + (p & 3) * 8;
  }
  const int rbase = (fr >> 1) * 128 + (((((fr & 1) << 2) | kg) ^ (fr >> 1)) << 4);
  const int sAo = wr * 64 * 64;
  const int sBo = wc * 64 * 64;

  f32x4 acc[MI][4] = {};

  auto stage = [&](int buf, int tk) {
    char* d = smem + buf * SLOT;
    gld_lds16(Ab + aoff + tk * 32, d + tid * 16);
    #pragma unroll
    for (int j = 0; j < CB; ++j)
      gld_lds16(Bb + boff[j] + tk * 32, d + ABYTES + (j * 512 + tid) * 16);
  };

  const int nt = K >> 5;
  stage(0, 0);
  stage(1, 1);
  asm volatile("s_waitcnt vmcnt(%0)" :: "n"(L) : "memory");
  __builtin_amdgcn_s_barrier();

  for (int t = 0; t < nt; ++t) {
    const char* base = smem + (t % 3) * SLOT;
    const bool st = (t + 2 < nt);
    if (st) stage((t + 2) % 3, t + 2);
    bf16x8 af[4], bfv[4];
    #pragma unroll
    for (int i = 0; i < 4; ++i)
      af[i] = *(const bf16x8*)(base + sAo + i * 1024 + rbase);
    #pragma unroll
    for (int ni = 0; ni < 4; ++ni)
      bfv[ni] = *(const bf16x8*)(base + ABYTES + sBo + ni * 1024 + rbase);
    asm volatile("s_waitcnt lgkmcnt(0)" ::: "memory");
    __builtin_amdgcn_sched_barrier(0);
    __builtin_amdgcn_s_setprio(1);
    #pragma unroll
    for (int i = 0; i < 4; ++i)
      #pragma unroll
      for (int ni = 0; ni < 4; ++ni)
        acc[i][ni] = __builtin_amdgcn_mfma_f32_16x16x32_bf16(
            af[i], bfv[ni], acc[i][ni], 0, 0, 0);
    __builtin_amdgcn_s_setprio(0);
    if (st)
      asm volatile("s_waitcnt vmcnt(%0)" :: "n"(L) : "memory");
    else if (t + 1 < nt)
      asm volatile("s_waitcnt vmcnt(0)" ::: "memory");
    if (t + 1 < nt)
      __builtin_amdgcn_s_barrier();
  }

  const int row0 = bx * BM_ + wr * 64 + kg * 4;
  const int coln = by * BN_ + wc * 64 + fr;
  #pragma unroll
  for (int mi = 0; mi < MI; ++mi) {
    #pragma unroll
    for (int ni = 0; ni < 4; ++ni) {
      int n = coln + ni * 16;
      float badd = 0.0f;
      if (BIAS_MODE == 3) badd = (n < 512) ? bias[n] : bias2[n - 512];
      #pragma unroll
      for (int j = 0; j < 4; ++j) {
        int m = row0 + mi * 16 + j;
        float v = acc[mi][ni][j];
        if (BIAS_MODE == 2) v += bias[m];
        else if (BIAS_MODE == 3) v += badd;
        if (SCALE) v *= scale;
        if (BIAS_MODE == 4) v *= bias[(size_t)bz * 2048 + m];
        if constexpr (sizeof(OutT) == 1) {
          int l = n & 63;
          ((u8*)Cp)[zc + (size_t)m * N + (size_t)(n & ~63) + pi64(l)] = f2f8(v);
        } else {
          size_t idx = zc + (size_t)m * N + n;
          if (RESID) v += resid[idx];
          if constexpr (sizeof(OutT) == 2) {
            Cp[idx] = (OutT)f2bf(v);
          } else {
            Cp[idx] = v;
          }
        }
      }
    }
  }
  (void)LP; (void)SMEXP;
}

// ---------------- fp8 TN GEMM: BK=64 K-tiles, BN templated ---------------
// Inputs fp8-e4m3 with pi64 interleave -> staging/ds_read byte-identical
// pattern to the verified bf16 kernel; one b128 read yields both K=32
// slices.  nt = K/64.  BN_=512 (scores): wave tile 64x128, acc 4x8, CB=4,
// ring-3 = 120KB -- amortizes the per-K-tile overhead over 2x MFMA.
// BN_=256 (PV): the R20 config.  SMEXP stores P''=exp2(s*log2e-4) (<=28,
// e4m3-safe; 2^-4 cancels via linv) and reduces row sums to LP (gy slabs).
// BIAS_MODE: 0 none, 4 *bias[bz*2048+m].
template <int BN_, int BIAS_MODE, int SCALE, typename OutT, int SMEXP>
__global__ __launch_bounds__(512, 1) void gemm_f8(
    const u8* __restrict__ A, const u8* __restrict__ B,
    OutT* __restrict__ Cp, const float* __restrict__ bias,
    float* __restrict__ LP, float scale, int K, int N, int ldaB, int ldbB,
    long sAb, long sBb, long sCb, int gx, int gy) {
  constexpr int MI = 4;
  constexpr int NI = BN_ / 64;             // 4 or 8
  constexpr int WN = BN_ / 4;              // 64 or 128
  constexpr int CB = BN_ / 128, L = 1 + CB;
  constexpr int ABYTES = 8192;             // A: 128 rows x 64B
  constexpr int SLOT = 8192 + BN_ * 64;
  extern __shared__ char smem[];
  const int tid = threadIdx.x;
  const int wave = tid >> 6, lane = tid & 63;
  const int wr = wave >> 2, wc = wave & 3;
  const int fr = lane & 15, kg = lane >> 4;

  const int nq = gridDim.x >> 3;
  const int sid = (blockIdx.x & 7) * nq + (blockIdx.x >> 3);
  const int bx = sid % gx;
  const int t1 = sid / gx;
  const int by = t1 % gy;
  const int bz = t1 / gy;

  const size_t zc = (size_t)bz * sCb;
  const u8* Ab = A + (size_t)bz * sAb + (size_t)bx * 128 * ldaB;
  const u8* Bb = B + (size_t)bz * sBb + (size_t)by * BN_ * ldbB;

  int aoff, boff[CB];
  {
    int pc = tid;
    int S = pc >> 3, p = (pc & 7) ^ (S & 7);
    aoff = (2 * S + (p >> 2)) * ldaB + (p & 3) * 16;
  }
  #pragma unroll
  for (int j = 0; j < CB; ++j) {
    int pc = j * 512 + tid;
    int S = pc >> 3, p = (pc & 7) ^ (S & 7);
    boff[j] = (2 * S + (p >> 2)) * ldbB + (p & 3) * 16;
  }
  const int rbase = (fr >> 1) * 128 + (((((fr & 1) << 2) | kg) ^ (fr >> 1)) << 4);
  const int sAo = wr * 4096;
  const int sBo = wc * WN * 64;

  f32x4 acc[MI][NI] = {};

  auto stage = [&](int buf, int tk) {
    char* d = smem + buf * SLOT;
    gld_lds16(Ab + aoff + tk * 64, d + tid * 16);
    #pragma unroll
    for (int j = 0; j < CB; ++j)
      gld_lds16(Bb + boff[j] + tk * 64, d + ABYTES + (j * 512 + tid) * 16);
  };

  const int nt = K >> 6;                   // 8 (scores) or 32 (PV)
  stage(0, 0);
  stage(1, 1);
  asm volatile("s_waitcnt vmcnt(%0)" :: "n"(L) : "memory");
  __builtin_amdgcn_s_barrier();

  for (int t = 0; t < nt; ++t) {
    const char* base = smem + (t % 3) * SLOT;
    const bool st = (t + 2 < nt);
    if (st) stage((t + 2) % 3, t + 2);
    long2v af[4], bfv[NI];
    #pragma unroll
    for (int i = 0; i < 4; ++i)
      af[i] = *(const long2v*)(base + sAo + i * 1024 + rbase);
    #pragma unroll
    for (int ni = 0; ni < NI; ++ni)
      bfv[ni] = *(const long2v*)(base + ABYTES + sBo + ni * 1024 + rbase);
    asm volatile("s_waitcnt lgkmcnt(0)" ::: "memory");
    __builtin_amdgcn_sched_barrier(0);
    __builtin_amdgcn_s_setprio(1);
    #pragma unroll
    for (int ksl = 0; ksl < 2; ++ksl)
      #pragma unroll
      for (int i = 0; i < 4; ++i)
        #pragma unroll
        for (int ni = 0; ni < NI; ++ni)
          acc[i][ni] = __builtin_amdgcn_mfma_f32_16x16x32_fp8_fp8(
              af[i][ksl], bfv[ni][ksl], acc[i][ni], 0, 0, 0);
    __builtin_amdgcn_s_setprio(0);
    if (st)
      asm volatile("s_waitcnt vmcnt(%0)" :: "n"(L) : "memory");
    else if (t + 1 < nt)
      asm volatile("s_waitcnt vmcnt(0)" ::: "memory");
    if (t + 1 < nt)
      __builtin_amdgcn_s_barrier();
  }

  float rs[MI][4];
  if constexpr (SMEXP) {
    #pragma unroll
    for (int mi = 0; mi < MI; ++mi)
      #pragma unroll
      for (int j = 0; j < 4; ++j) rs[mi][j] = 0.f;
  }

  const int row0 = bx * 128 + wr * 64 + kg * 4;
  const int coln = by * BN_ + wc * WN + fr;
  #pragma unroll
  for (int mi = 0; mi < MI; ++mi) {
    #pragma unroll
    for (int ni = 0; ni < NI; ++ni) {
      int n = coln + ni * 16;
      #pragma unroll
      for (int j = 0; j < 4; ++j) {
        int m = row0 + mi * 16 + j;
        float v = acc[mi][ni][j];
        if (SCALE) v *= scale;
        if constexpr (SMEXP) {
          v = exp2f(fmaf(v, LOG2E, -4.0f));   // 2^-4 shift: e4m3-safe
          rs[mi][j] += v;
        }
        if (BIAS_MODE == 4) v *= bias[(size_t)bz * 2048 + m];
        if constexpr (sizeof(OutT) == 1) {
          int l = n & 63;
          ((u8*)Cp)[zc + (size_t)m * N + (size_t)(n & ~63) + pi64(l)] = f2f8(v);
        } else {
          Cp[zc + (size_t)m * N + n] = (OutT)f2bf(v);
        }
      }
    }
  }

  if constexpr (SMEXP) {
    float* redl = (float*)smem;              // [128][4]
    __syncthreads();
    #pragma unroll
    for (int mi = 0; mi < MI; ++mi) {
      #pragma unroll
      for (int j = 0; j < 4; ++j) {
        float l = rs[mi][j];
        #pragma unroll
        for (int msk = 1; msk < 16; msk <<= 1)
          l += __shfl_xor(l, msk, 64);
        if (fr == 0) {
          int rr = wr * 64 + mi * 16 + kg * 4 + j;
          redl[rr * 4 + wc] = l;
        }
      }
    }
    __syncthreads();
    if (tid < 128) {
      float l = redl[tid * 4] + redl[tid * 4 + 1] +
                redl[tid * 4 + 2] + redl[tid * 4 + 3];
      LP[((size_t)bz * gy + by) * 2048 + bx * 128 + tid] = l;
    }
  }
}

extern "C" void kernel_launch(void* const* d_in, const int* in_sizes, int n_in,
                              void* d_out, int out_size, void* d_ws,
                              size_t ws_size, hipStream_t stream) {
  const float* x     = (const float*)d_in[0];
  const float* gamma = (const float*)d_in[1];
  const float* beta  = (const float*)d_in[2];
  const float* wq    = (const float*)d_in[3];
  const float* bq    = (const float*)d_in[4];
  const float* wk    = (const float*)d_in[5];
  const float* bk    = (const float*)d_in[6];
  const float* wv    = (const float*)d_in[7];
  const float* bv    = (const float*)d_in[8];
  const float* wp    = (const float*)d_in[9];
  const float* bp    = (const float*)d_in[10];
  float* out = (float*)d_out;

  char* ws = (char*)d_ws;
  u16* wq_bf = (u16*)ws;                    // wq,wk contiguous => combined B
  u16* wv_bf = wq_bf + 524288;
  u16* wp_bf = wv_bf + 262144;
  u16* hT = (u16*)(ws + 4 * 524288);        // bf16 [8][2048][512]
  u8*  qk8 = (u8*)(hT + 8388608);           // fp8-pi [8][2048][1024] (q|k)
  u8*  vB8 = qk8 + 16777216;                // fp8-pi [8][512][2048]
  u16* oT  = (u16*)(vB8 + 8388608);         // bf16 [8][2048][512]
  u8*  sc8 = (u8*)(oT + 8388608);           // fp8-pi [8][2048][2048] P''
  float* lpart = (float*)(sc8 + 33554432);  // [8][4][2048]
  float* linv  = lpart + 131072;            // [8][2048]

  const long sWC = (long)WDIM * CDIM;       // 1048576
  const long sCW = (long)CDIM * WDIM;
  const long sQK = (long)WDIM * 1024;       // bytes per batch of qk8
  const long sWW = (long)WDIM * WDIM;       // bytes per batch of sc8

  const int SMEM = 3 * (128 + 256) * 64;    // 73728
  const int SMEM512 = 3 * (8192 + 512 * 64);// 122880
  const int GN_SMEM = 16 * 2052 * 2;        // 65664
  (void)hipFuncSetAttribute((const void*)&gn_fused,
      hipFuncAttributeMaxDynamicSharedMemorySize, GN_SMEM);
  (void)hipFuncSetAttribute((const void*)&gemm_tn<3, 0, 0, u8, 0>,
      hipFuncAttributeMaxDynamicSharedMemorySize, SMEM);
  (void)hipFuncSetAttribute((const void*)&gemm_tn<2, 0, 0, u8, 0>,
      hipFuncAttributeMaxDynamicSharedMemorySize, SMEM);
  (void)hipFuncSetAttribute((const void*)&gemm_f8<512, 0, 1, u8, 1>,
      hipFuncAttributeMaxDynamicSharedMemorySize, SMEM512);
  (void)hipFuncSetAttribute((const void*)&gemm_f8<256, 4, 0, u16, 0>,
      hipFuncAttributeMaxDynamicSharedMemorySize, SMEM);
  (void)hipFuncSetAttribute((const void*)&gemm_tn<2, 1, 0, float, 0>,
      hipFuncAttributeMaxDynamicSharedMemorySize, SMEM);

  cvt_weights<<<1024, 256, 0, stream>>>(wq, wk, wv, wp, wq_bf);
  gn_fused<<<BDIM * NGRP, 512, GN_SMEM, stream>>>(x, gamma, beta, hT);

  const float scale = 0.04419417382415922f;  // 512^-0.5

  // qk8[b][w][0:512]=fp8(h.Wq^T+bq) ; [512:1024]=fp8(h.Wk^T+bk)  (512 blk)
  gemm_tn<3, 0, 0, u8, 0><<<512, 512, SMEM, stream>>>(
      hT, wq_bf, qk8, bq, bk, nullptr, nullptr, 1.f, 512, 1024,
      512, 512, sWC, 0, sQK, 16, 4);
  // vB8[b][c][w] = fp8(Wv . h + bv)                              (256 blk)
  gemm_tn<2, 0, 0, u8, 0><<<256, 512, SMEM, stream>>>(
      wv_bf, hT, vB8, bv, nullptr, nullptr, nullptr, 1.f, 512, 2048,
      512, 512, 0, sWC, sCW, 4, 8);
  // sc8 = fp8(exp2(qk*c^-0.5*log2e - 4)); row sums -> lpart      (512 blk)
  gemm_f8<512, 0, 1, u8, 1><<<512, 512, SMEM512, stream>>>(
      qk8, qk8 + 512, sc8, nullptr, lpart, scale, 512, 2048,
      1024, 1024, sQK, sQK, sWW, 16, 4);
  // combine partial row sums (4 slabs) -> linv                   (64 blk)
  sm_combine<4><<<64, 256, 0, stream>>>(lpart, linv);
  // oT[b][i][c] = (P'' . v^T) * linv[i]  (bf16 out)              (256 blk)
  gemm_f8<256, 4, 0, u16, 0><<<256, 512, SMEM, stream>>>(
      sc8, vB8, oT, linv, nullptr, 1.f, 2048, 512,
      2048, 2048, sWW, sCW, sWC, 16, 2);
  // out[b][c][i] = wp . o + bp + x                               (256 blk)
  gemm_tn<2, 1, 0, float, 0><<<256, 512, SMEM, stream>>>(
      wp_bf, oT, out, bp, nullptr, x, nullptr, 1.f, 512, 2048,
      512, 512, 0, sWC, sCW, 4, 8);
}

// Round 23
// 148.951 us; speedup vs baseline: 1.1062x; 1.1062x over previous
//
#include <hip/hip_runtime.h>
#include <hip/hip_bf16.h>
#include <stdint.h>

#define CDIM 512
#define WDIM 2048
#define BDIM 8
#define NGRP 32
#define LOG2E 1.4426950408889634f

typedef unsigned short u16;
typedef unsigned char u8;
typedef unsigned long long u64;
typedef __attribute__((ext_vector_type(8))) short bf16x8;
typedef __attribute__((ext_vector_type(4))) float f32x4;
typedef __attribute__((ext_vector_type(2))) long long2v;

__device__ __forceinline__ float bf2f(u16 u) {
  return __builtin_bit_cast(float, (uint32_t)(u) << 16);
}
__device__ __forceinline__ u16 f2bf(float f) {
  return __builtin_bit_cast(u16, __float2bfloat16(f));
}
__device__ __forceinline__ u8 f2f8(float f) {
  // OCP e4m3 via HW cvt (saturating); our values are far from 448.
  return (u8)(__builtin_amdgcn_cvt_pk_fp8_f32(f, 0.f, 0, false));
}

__device__ __forceinline__ void gld_lds16(const void* g, void* l) {
  __builtin_amdgcn_global_load_lds(
      (const __attribute__((address_space(1))) uint32_t*)(uintptr_t)(g),
      (__attribute__((address_space(3))) uint32_t*)(uintptr_t)(l),
      16, 0, 0);
}

// fp8 k-octet interleave within each 64-byte k-window: stored 16B chunk c
// holds global octets (c, c+4) -> one ds_read_b128 yields both K=32 slices.
__device__ __forceinline__ int pi64(int l) {
  return ((l >> 3) & 3) * 16 + ((l >> 5) & 1) * 8 + (l & 7);
}

// ---------------- weights: wq|wk, wv -> fp8-pi ; wp -> bf16 ----------------
__global__ __launch_bounds__(256) void cvt_weights(
    const float* __restrict__ wq, const float* __restrict__ wk,
    const float* __restrict__ wv, const float* __restrict__ wp,
    u8* __restrict__ wqk8, u8* __restrict__ wv8, u16* __restrict__ wp_bf) {
  const int t = blockIdx.x * 256 + threadIdx.x;   // 16384 threads
  if (t < 8192) {                       // wqk: 1024 rows x 8 windows
    int row = t >> 3, c0 = (t & 7) * 64;
    const float* src = (row < 512) ? wq + (size_t)row * 512 + c0
                                   : wk + (size_t)(row - 512) * 512 + c0;
    u8 buf[64];
    #pragma unroll
    for (int l = 0; l < 64; ++l) buf[pi64(l)] = f2f8(src[l]);
    u8* dst = wqk8 + (size_t)row * 512 + c0;
    #pragma unroll
    for (int q = 0; q < 4; ++q)
      *(uint4*)(dst + q * 16) = *(const uint4*)(buf + q * 16);
  } else if (t < 12288) {               // wv: 512 rows x 8 windows
    int t2 = t - 8192;
    int row = t2 >> 3, c0 = (t2 & 7) * 64;
    const float* src = wv + (size_t)row * 512 + c0;
    u8 buf[64];
    #pragma unroll
    for (int l = 0; l < 64; ++l) buf[pi64(l)] = f2f8(src[l]);
    u8* dst = wv8 + (size_t)row * 512 + c0;
    #pragma unroll
    for (int q = 0; q < 4; ++q)
      *(uint4*)(dst + q * 16) = *(const uint4*)(buf + q * 16);
  }
  #pragma unroll
  for (int j = 0; j < 16; ++j) {        // wp bf16 (16384*16 = 262144)
    int i = t * 16 + j;
    wp_bf[i] = f2bf(wp[i]);
  }
}

// ---------------- fused groupnorm -> h8 fp8-pi, x read ONCE ----------------
__global__ __launch_bounds__(512) void gn_fused(
    const float* __restrict__ x, const float* __restrict__ gamma,
    const float* __restrict__ beta, u8* __restrict__ h8) {
  extern __shared__ u16 hbuf[];            // [16][2052] padded
  __shared__ float red[2][8];
  __shared__ float mrsh[2];
  const int bg = blockIdx.x;               // b*32+g
  const int b = bg >> 5, g = bg & 31;
  const int tid = threadIdx.x;
  const float4* xp = (const float4*)(x + (size_t)bg * 16 * WDIM);
  float s = 0.f, s2 = 0.f;
  for (int i = tid; i < 16 * WDIM / 4; i += 512) {
    float4 v = xp[i];
    s += v.x + v.y + v.z + v.w;
    s2 = fmaf(v.x, v.x, s2); s2 = fmaf(v.y, v.y, s2);
    s2 = fmaf(v.z, v.z, s2); s2 = fmaf(v.w, v.w, s2);
    int e = i * 4;
    int cc = e >> 11, w = e & 2047;
    u16* p = &hbuf[cc * 2052 + w];
    p[0] = f2bf(v.x); p[1] = f2bf(v.y); p[2] = f2bf(v.z); p[3] = f2bf(v.w);
  }
  for (int off = 32; off; off >>= 1) {
    s  += __shfl_xor(s, off, 64);
    s2 += __shfl_xor(s2, off, 64);
  }
  if ((tid & 63) == 0) { red[0][tid >> 6] = s; red[1][tid >> 6] = s2; }
  __syncthreads();
  if (tid == 0) {
    float S = 0.f, S2 = 0.f;
    #pragma unroll
    for (int i = 0; i < 8; ++i) { S += red[0][i]; S2 += red[1][i]; }
    const float inv_n = 1.0f / (16.0f * WDIM);
    float m = S * inv_n;
    float var = S2 * inv_n - m * m;
    mrsh[0] = m; mrsh[1] = rsqrtf(var + 1e-6f);
  }
  __syncthreads();
  const float m = mrsh[0], r = mrsh[1];
  float ga[16], bb[16];
  #pragma unroll
  for (int cc = 0; cc < 16; ++cc) {
    float gm = gamma[g * 16 + cc] * r;
    ga[cc] = gm;
    bb[cc] = beta[g * 16 + cc] - m * gm;
  }
  const int gq = g & 3;
  const int off0 = ((2 * gq) & 3) * 16 + (gq >> 1) * 8;
  const int off1 = ((2 * gq + 1) & 3) * 16 + (gq >> 1) * 8;
  #pragma unroll
  for (int rr = 0; rr < 4; ++rr) {
    int w = rr * 512 + tid;
    u8 ov[16];
    #pragma unroll
    for (int cc = 0; cc < 16; ++cc)
      ov[cc] = f2f8(fmaf(bf2f(hbuf[cc * 2052 + w]), ga[cc], bb[cc]));
    u8* dst = h8 + ((size_t)b * WDIM + w) * CDIM + (g >> 2) * 64;
    *(u64*)(dst + off0) = *(const u64*)(&ov[0]);
    *(u64*)(dst + off1) = *(const u64*)(&ov[8]);
  }
}

// ---------------- combine per-block row-sum partials -> 1/rowsum ----------
template <int NP>
__global__ __launch_bounds__(256) void sm_combine(
    const float* __restrict__ lpart, float* __restrict__ linv) {
  int idx = blockIdx.x * 256 + threadIdx.x;   // 16384 = 8*2048
  int b = idx >> 11, i = idx & 2047;
  float l = 0.f;
  #pragma unroll
  for (int p = 0; p < NP; ++p)
    l += lpart[((size_t)b * NP + p) * 2048 + i];
  linv[idx] = 1.0f / l;
}

// ---------------- bf16 TN GEMM (R16 skeleton; final projection) -----------
// C[m][n] = sum_k A[m][k]*B[n][k]. BM=128, BN=256, wave tile 64x64.
// BK=32, ring-3 LDS (72KB), stage 2 ahead, counted vmcnt(3), one closing
// barrier per K-tile; bijective XCD swizzle; verified conflict-free
// both-sides LDS swizzle.  BIAS_MODE 2: +bias[m].  RESID: +resid.
template <int BIAS_MODE, int RESID, typename OutT>
__global__ __launch_bounds__(512, 1) void gemm_tn(
    const u16* __restrict__ A, const u16* __restrict__ B,
    OutT* __restrict__ Cp, const float* __restrict__ bias,
    const float* __restrict__ resid, float scale, int K, int N,
    int lda, int ldb, long sAb, long sBb, long sCb, int gx, int gy) {
  constexpr int MI = 4;
  constexpr int CB = 2, L = 3;
  constexpr int ABYTES = 8192;
  constexpr int SLOT = 24576;
  extern __shared__ char smem[];
  const int tid = threadIdx.x;
  const int wave = tid >> 6, lane = tid & 63;
  const int wr = wave >> 2, wc = wave & 3;
  const int fr = lane & 15, kg = lane >> 4;

  const int nq = gridDim.x >> 3;
  const int sid = (blockIdx.x & 7) * nq + (blockIdx.x >> 3);
  const int bx = sid % gx;
  const int t1 = sid / gx;
  const int by = t1 % gy;
  const int bz = t1 / gy;

  const size_t zc = (size_t)bz * sCb;
  const u16* Ab = A + (size_t)bz * sAb + (size_t)bx * 128 * lda;
  const u16* Bb = B + (size_t)bz * sBb + (size_t)by * 256 * ldb;

  int aoff, boff[CB];
  {
    int pc = tid;
    int S = pc >> 3, p = (pc & 7) ^ (S & 7);
    aoff = (2 * S + (p >> 2)) * lda + (p & 3) * 8;
  }
  #pragma unroll
  for (int j = 0; j < CB; ++j) {
    int pc = j * 512 + tid;
    int S = pc >> 3, p = (pc & 7) ^ (S & 7);
    boff[j] = (2 * S + (p >> 2)) * ldb + (p & 3) * 8;
  }
  const int rbase = (fr >> 1) * 128 + (((((fr & 1) << 2) | kg) ^ (fr >> 1)) << 4);
  const int sAo = wr * 4096;
  const int sBo = wc * 4096;

  f32x4 acc[MI][4] = {};

  auto stage = [&](int buf, int tk) {
    char* d = smem + buf * SLOT;
    gld_lds16(Ab + aoff + tk * 32, d + tid * 16);
    #pragma unroll
    for (int j = 0; j < CB; ++j)
      gld_lds16(Bb + boff[j] + tk * 32, d + ABYTES + (j * 512 + tid) * 16);
  };

  const int nt = K >> 5;
  stage(0, 0);
  stage(1, 1);
  asm volatile("s_waitcnt vmcnt(%0)" :: "n"(L) : "memory");
  __builtin_amdgcn_s_barrier();

  for (int t = 0; t < nt; ++t) {
    const char* base = smem + (t % 3) * SLOT;
    const bool st = (t + 2 < nt);
    if (st) stage((t + 2) % 3, t + 2);
    bf16x8 af[4], bfv[4];
    #pragma unroll
    for (int i = 0; i < 4; ++i)
      af[i] = *(const bf16x8*)(base + sAo + i * 1024 + rbase);
    #pragma unroll
    for (int ni = 0; ni < 4; ++ni)
      bfv[ni] = *(const bf16x8*)(base + ABYTES + sBo + ni * 1024 + rbase);
    asm volatile("s_waitcnt lgkmcnt(0)" ::: "memory");
    __builtin_amdgcn_sched_barrier(0);
    __builtin_amdgcn_s_setprio(1);
    #pragma unroll
    for (int i = 0; i < 4; ++i)
      #pragma unroll
      for (int ni = 0; ni < 4; ++ni)
        acc[i][ni] = __builtin_amdgcn_mfma_f32_16x16x32_bf16(
            af[i], bfv[ni], acc[i][ni], 0, 0, 0);
    __builtin_amdgcn_s_setprio(0);
    if (st)
      asm volatile("s_waitcnt vmcnt(%0)" :: "n"(L) : "memory");
    else if (t + 1 < nt)
      asm volatile("s_waitcnt vmcnt(0)" ::: "memory");
    if (t + 1 < nt)
      __builtin_amdgcn_s_barrier();
  }

  const int row0 = bx * 128 + wr * 64 + kg * 4;
  const int coln = by * 256 + wc * 64 + fr;
  #pragma unroll
  for (int mi = 0; mi < MI; ++mi) {
    #pragma unroll
    for (int ni = 0; ni < 4; ++ni) {
      int n = coln + ni * 16;
      #pragma unroll
      for (int j = 0; j < 4; ++j) {
        int m = row0 + mi * 16 + j;
        float v = acc[mi][ni][j];
        if (BIAS_MODE == 2) v += bias[m];
        size_t idx = zc + (size_t)m * N + n;
        if (RESID) v += resid[idx];
        if constexpr (sizeof(OutT) == 2) {
          Cp[idx] = (OutT)f2bf(v);
        } else {
          Cp[idx] = v;
        }
      }
    }
  }
  (void)scale;
}

// ---------------- fp8 TN GEMM: BK=64 K-tiles (R20 proven) -----------------
// Inputs fp8-e4m3 with pi64 interleave -> staging/ds_read byte-identical
// pattern to the bf16 kernel; one b128 read yields both K=32 slices.
// nt = K/64.  SMEXP stores P''=exp2(s*log2e-4) (<=28, e4m3-safe; 2^-4
// cancels via linv) and reduces row sums to LP (gy slabs).
// BIAS_MODE: 0 none, 2 +bias[m], 3 split-n (bias/bias2), 4 *bias[bz*2048+m].
template <int BIAS_MODE, int SCALE, typename OutT, int SMEXP>
__global__ __launch_bounds__(512, 1) void gemm_f8(
    const u8* __restrict__ A, const u8* __restrict__ B,
    OutT* __restrict__ Cp, const float* __restrict__ bias,
    const float* __restrict__ bias2, float* __restrict__ LP,
    float scale, int K, int N, int ldaB, int ldbB,
    long sAb, long sBb, long sCb, int gx, int gy) {
  constexpr int MI = 4;
  constexpr int CB = 2, L = 3;
  constexpr int ABYTES = 8192;             // A: 128 rows x 64B
  constexpr int SLOT = 24576;              // + B: 256 rows x 64B
  extern __shared__ char smem[];
  const int tid = threadIdx.x;
  const int wave = tid >> 6, lane = tid & 63;
  const int wr = wave >> 2, wc = wave & 3;
  const int fr = lane & 15, kg = lane >> 4;

  const int nq = gridDim.x >> 3;
  const int sid = (blockIdx.x & 7) * nq + (blockIdx.x >> 3);
  const int bx = sid % gx;
  const int t1 = sid / gx;
  const int by = t1 % gy;
  const int bz = t1 / gy;

  const size_t zc = (size_t)bz * sCb;
  const u8* Ab = A + (size_t)bz * sAb + (size_t)bx * 128 * ldaB;
  const u8* Bb = B + (size_t)bz * sBb + (size_t)by * 256 * ldbB;

  int aoff, boff[CB];
  {
    int pc = tid;
    int S = pc >> 3, p = (pc & 7) ^ (S & 7);
    aoff = (2 * S + (p >> 2)) * ldaB + (p & 3) * 16;
  }
  #pragma unroll
  for (int j = 0; j < CB; ++j) {
    int pc = j * 512 + tid;
    int S = pc >> 3, p = (pc & 7) ^ (S & 7);
    boff[j] = (2 * S + (p >> 2)) * ldbB + (p & 3) * 16;
  }
  const int rbase = (fr >> 1) * 128 + (((((fr & 1) << 2) | kg) ^ (fr >> 1)) << 4);
  const int sAo = wr * 4096;
  const int sBo = wc * 4096;

  f32x4 acc[MI][4] = {};

  auto stage = [&](int buf, int tk) {
    char* d = smem + buf * SLOT;
    gld_lds16(Ab + aoff + tk * 64, d + tid * 16);
    #pragma unroll
    for (int j = 0; j < CB; ++j)
      gld_lds16(Bb + boff[j] + tk * 64, d + ABYTES + (j * 512 + tid) * 16);
  };

  const int nt = K >> 6;                   // 8 (qk/v/scores) or 32 (PV)
  stage(0, 0);
  stage(1, 1);
  asm volatile("s_waitcnt vmcnt(%0)" :: "n"(L) : "memory");
  __builtin_amdgcn_s_barrier();

  for (int t = 0; t < nt; ++t) {
    const char* base = smem + (t % 3) * SLOT;
    const bool st = (t + 2 < nt);
    if (st) stage((t + 2) % 3, t + 2);
    long2v af[4], bfv[4];
    #pragma unroll
    for (int i = 0; i < 4; ++i)
      af[i] = *(const long2v*)(base + sAo + i * 1024 + rbase);
    #pragma unroll
    for (int ni = 0; ni < 4; ++ni)
      bfv[ni] = *(const long2v*)(base + ABYTES + sBo + ni * 1024 + rbase);
    asm volatile("s_waitcnt lgkmcnt(0)" ::: "memory");
    __builtin_amdgcn_sched_barrier(0);
    __builtin_amdgcn_s_setprio(1);
    #pragma unroll
    for (int ksl = 0; ksl < 2; ++ksl)
      #pragma unroll
      for (int i = 0; i < 4; ++i)
        #pragma unroll
        for (int ni = 0; ni < 4; ++ni)
          acc[i][ni] = __builtin_amdgcn_mfma_f32_16x16x32_fp8_fp8(
              af[i][ksl], bfv[ni][ksl], acc[i][ni], 0, 0, 0);
    __builtin_amdgcn_s_setprio(0);
    if (st)
      asm volatile("s_waitcnt vmcnt(%0)" :: "n"(L) : "memory");
    else if (t + 1 < nt)
      asm volatile("s_waitcnt vmcnt(0)" ::: "memory");
    if (t + 1 < nt)
      __builtin_amdgcn_s_barrier();
  }

  float rs[MI][4];
  if constexpr (SMEXP) {
    #pragma unroll
    for (int mi = 0; mi < MI; ++mi)
      #pragma unroll
      for (int j = 0; j < 4; ++j) rs[mi][j] = 0.f;
  }

  const int row0 = bx * 128 + wr * 64 + kg * 4;
  const int coln = by * 256 + wc * 64 + fr;
  #pragma unroll
  for (int mi = 0; mi < MI; ++mi) {
    #pragma unroll
    for (int ni = 0; ni < 4; ++ni) {
      int n = coln + ni * 16;
      float badd = 0.0f;
      if (BIAS_MODE == 3) badd = (n < 512) ? bias[n] : bias2[n - 512];
      #pragma unroll
      for (int j = 0; j < 4; ++j) {
        int m = row0 + mi * 16 + j;
        float v = acc[mi][ni][j];
        if (BIAS_MODE == 2) v += bias[m];
        else if (BIAS_MODE == 3) v += badd;
        if (SCALE) v *= scale;
        if constexpr (SMEXP) {
          v = exp2f(fmaf(v, LOG2E, -4.0f));   // 2^-4 shift: e4m3-safe
          rs[mi][j] += v;
        }
        if (BIAS_MODE == 4) v *= bias[(size_t)bz * 2048 + m];
        if constexpr (sizeof(OutT) == 1) {
          int l = n & 63;
          ((u8*)Cp)[zc + (size_t)m * N + (size_t)(n & ~63) + pi64(l)] = f2f8(v);
        } else {
          Cp[zc + (size_t)m * N + n] = (OutT)f2bf(v);
        }
      }
    }
  }

  if constexpr (SMEXP) {
    float* redl = (float*)smem;              // [128][4]
    __syncthreads();
    #pragma unroll
    for (int mi = 0; mi < MI; ++mi) {
      #pragma unroll
      for (int j = 0; j < 4; ++j) {
        float l = rs[mi][j];
        #pragma unroll
        for (int msk = 1; msk < 16; msk <<= 1)
          l += __shfl_xor(l, msk, 64);
        if (fr == 0) {
          int rr = wr * 64 + mi * 16 + kg * 4 + j;
          redl[rr * 4 + wc] = l;
        }
      }
    }
    __syncthreads();
    if (tid < 128) {
      float l = redl[tid * 4] + redl[tid * 4 + 1] +
                redl[tid * 4 + 2] + redl[tid * 4 + 3];
      LP[((size_t)bz * gy + by) * 2048 + bx * 128 + tid] = l;
    }
  }
}

extern "C" void kernel_launch(void* const* d_in, const int* in_sizes, int n_in,
                              void* d_out, int out_size, void* d_ws,
                              size_t ws_size, hipStream_t stream) {
  const float* x     = (const float*)d_in[0];
  const float* gamma = (const float*)d_in[1];
  const float* beta  = (const float*)d_in[2];
  const float* wq    = (const float*)d_in[3];
  const float* bq    = (const float*)d_in[4];
  const float* wk    = (const float*)d_in[5];
  const float* bk    = (const float*)d_in[6];
  const float* wv    = (const float*)d_in[7];
  const float* bv    = (const float*)d_in[8];
  const float* wp    = (const float*)d_in[9];
  const float* bp    = (const float*)d_in[10];
  float* out = (float*)d_out;

  char* p = (char*)d_ws;
  u8*  wqk8 = (u8*)p;           p += 524288;     // fp8-pi [1024][512]
  u8*  wv8  = (u8*)p;           p += 262144;     // fp8-pi [512][512]
  u16* wp_bf = (u16*)p;         p += 524288;     // bf16 [512][512]
  u8*  h8   = (u8*)p;           p += 8388608;    // fp8-pi [8][2048][512]
  u8*  qk8  = (u8*)p;           p += 16777216;   // fp8-pi [8][2048][1024]
  u8*  vB8  = (u8*)p;           p += 8388608;    // fp8-pi [8][512][2048]
  u16* oT   = (u16*)p;          p += 16777216;   // bf16 [8][2048][512]
  u8*  sc8  = (u8*)p;           p += 33554432;   // fp8-pi [8][2048][2048]
  float* lpart = (float*)p;     p += 524288;     // [8][8][2048]
  float* linv  = (float*)p;                      // [8][2048]

  const long sWC = (long)WDIM * CDIM;       // 1048576 (elems / bytes)
  const long sCW = (long)CDIM * WDIM;
  const long sQK = (long)WDIM * 1024;       // bytes per batch of qk8
  const long sWW = (long)WDIM * WDIM;       // bytes per batch of sc8

  const int SMEM = 3 * (128 + 256) * 64;    // 73728
  const int GN_SMEM = 16 * 2052 * 2;        // 65664
  (void)hipFuncSetAttribute((const void*)&gn_fused,
      hipFuncAttributeMaxDynamicSharedMemorySize, GN_SMEM);
  (void)hipFuncSetAttribute((const void*)&gemm_f8<3, 0, u8, 0>,
      hipFuncAttributeMaxDynamicSharedMemorySize, SMEM);
  (void)hipFuncSetAttribute((const void*)&gemm_f8<2, 0, u8, 0>,
      hipFuncAttributeMaxDynamicSharedMemorySize, SMEM);
  (void)hipFuncSetAttribute((const void*)&gemm_f8<0, 1, u8, 1>,
      hipFuncAttributeMaxDynamicSharedMemorySize, SMEM);
  (void)hipFuncSetAttribute((const void*)&gemm_f8<4, 0, u16, 0>,
      hipFuncAttributeMaxDynamicSharedMemorySize, SMEM);
  (void)hipFuncSetAttribute((const void*)&gemm_tn<2, 1, float>,
      hipFuncAttributeMaxDynamicSharedMemorySize, SMEM);

  cvt_weights<<<64, 256, 0, stream>>>(wq, wk, wv, wp, wqk8, wv8, wp_bf);
  gn_fused<<<BDIM * NGRP, 512, GN_SMEM, stream>>>(x, gamma, beta, h8);

  const float scale = 0.04419417382415922f;  // 512^-0.5

  // qk8[b][w][0:512]=fp8(h.Wq^T+bq) ; [512:1024]=fp8(h.Wk^T+bk)  (512 blk)
  gemm_f8<3, 0, u8, 0><<<512, 512, SMEM, stream>>>(
      h8, wqk8, qk8, bq, bk, nullptr, 1.f, 512, 1024, 512, 512,
      sWC, 0, sQK, 16, 4);
  // vB8[b][c][w] = fp8(Wv . h + bv)                              (256 blk)
  gemm_f8<2, 0, u8, 0><<<256, 512, SMEM, stream>>>(
      wv8, h8, vB8, bv, nullptr, nullptr, 1.f, 512, 2048, 512, 512,
      0, sWC, sCW, 4, 8);
  // sc8 = fp8(exp2(qk*c^-0.5*log2e - 4)); row sums -> lpart     (1024 blk)
  gemm_f8<0, 1, u8, 1><<<1024, 512, SMEM, stream>>>(
      qk8, qk8 + 512, sc8, nullptr, nullptr, lpart, scale, 512, 2048,
      1024, 1024, sQK, sQK, sWW, 16, 8);
  // combine partial row sums -> linv                             (64 blk)
  sm_combine<8><<<64, 256, 0, stream>>>(lpart, linv);
  // oT[b][i][c] = (P'' . v^T) * linv[i]  (bf16 out)              (256 blk)
  gemm_f8<4, 0, u16, 0><<<256, 512, SMEM, stream>>>(
      sc8, vB8, oT, linv, nullptr, nullptr, 1.f, 2048, 512, 2048, 2048,
      sWW, sCW, sWC, 16, 2);
  // out[b][c][i] = wp . o + bp + x                               (256 blk)
  gemm_tn<2, 1, float><<<256, 512, SMEM, stream>>>(
      wp_bf, oT, out, bp, x, 1.f, 512, 2048, 512, 512,
      0, sWC, sCW, 4, 8);
}